// Round 1
// baseline (1493.283 us; speedup 1.0000x reference)
//
#include <hip/hip_runtime.h>

// Actor_attf_single — MI355X (gfx950)
// R10: weights via LDS instead of SMEM. Ledger: R8=329us, R9 (wave-split
// TLP)=352us => more waves did NOT hide the stalls. Root cause theory:
// weight reads are s_load (SMEM), and SMEM returns OUT-OF-ORDER on CDNA,
// so every weight-dependent wait is a full `s_waitcnt lgkmcnt(0)` drain of
// the whole scalar prefetch queue — the inner loop is a hard
// load-burst/drain/FMA-burst serialization no amount of TLP fixes.
// Fix: stage all 4754 weight dwords (19KB) into LDS once per block;
// ds_read is IN-ORDER => compiler emits counted lgkmcnt(N) waits and
// pipelines weight reads ahead. Uniform address => broadcast, 0 conflicts.
//   - math is verbatim R9 (same FMA order, same online softmax) =>
//     absmax must stay bit-identical at 0.00390625
//   - role split kept (role 0 = self+other+head, role 1 = self+food,
//     fpool handoff via padded LDS)

#define LN_EPS 1e-5f

struct Weights {
  const float* __restrict__ en_W1; const float* __restrict__ en_b1;
  const float* __restrict__ en_W2; const float* __restrict__ en_b2;
  const float* __restrict__ oa_W1; const float* __restrict__ oa_b1;
  const float* __restrict__ oa_W2; const float* __restrict__ oa_b2;
  const float* __restrict__ go_W1; const float* __restrict__ go_b1;
  const float* __restrict__ go_W2; const float* __restrict__ go_b2;
  const float* __restrict__ oa_g;  const float* __restrict__ oa_b;
  const float* __restrict__ go_g;  const float* __restrict__ go_b;
  const float* __restrict__ a_W1;  const float* __restrict__ a_b1;
  const float* __restrict__ a_W2;  const float* __restrict__ a_b2;
  const float* __restrict__ a_W3;  const float* __restrict__ a_b3;
};

// LDS weight-pool offsets (dwords)
constexpr int O_EN_W1 = 0;      // 128
constexpr int O_EN_B1 = 128;    // 32
constexpr int O_EN_W2 = 160;    // 512
constexpr int O_EN_B2 = 672;    // 16
constexpr int O_OA_W1 = 688;    // 128
constexpr int O_OA_B1 = 816;    // 32
constexpr int O_OA_W2 = 848;    // 512
constexpr int O_OA_B2 = 1360;   // 16
constexpr int O_GO_W1 = 1376;   // 64
constexpr int O_GO_B1 = 1440;   // 32
constexpr int O_GO_W2 = 1472;   // 512
constexpr int O_GO_B2 = 1984;   // 16
constexpr int O_OA_G  = 2000;   // 16
constexpr int O_OA_B  = 2016;   // 16
constexpr int O_GO_G  = 2032;   // 16
constexpr int O_GO_B  = 2048;   // 16
constexpr int O_A_W1  = 2064;   // 1536
constexpr int O_A_B1  = 3600;   // 32
constexpr int O_A_W2  = 3632;   // 1024
constexpr int O_A_B2  = 4656;   // 32
constexpr int O_A_W3  = 4688;   // 64
constexpr int O_A_B3  = 4752;   // 2
constexpr int W_TOTAL = 4754;   // 19016 bytes

__device__ __forceinline__ float2 ld2(const float* __restrict__ p) {
  return *reinterpret_cast<const float2*>(p);
}

__device__ __forceinline__ void stage(float* __restrict__ dst,
                                      const float* __restrict__ src,
                                      int n, int tid) {
#pragma unroll 1
  for (int i = tid; i < n; i += 256) dst[i] = src[i];
}

__global__ __launch_bounds__(256)
void actor_fwd(const float* __restrict__ s_input, Weights W,
               float* __restrict__ out, int bsz) {
  __shared__ float sw[W_TOTAL];
  __shared__ float fpool[2][64][17];         // +1 pad: conflict-free

  const int tid     = threadIdx.x;
  const int lane    = tid & 63;
  const int wv      = tid >> 6;              // 0..3
  const int pairIdx = wv >> 1;               // 0..1  (64-row group in block)
  const int role    = wv & 1;                // 0: other+head, 1: food

  // ---- one-time cooperative weight staging: global -> LDS --------------
  stage(sw + O_EN_W1, W.en_W1, 128, tid);
  stage(sw + O_EN_B1, W.en_b1,  32, tid);
  stage(sw + O_EN_W2, W.en_W2, 512, tid);
  stage(sw + O_EN_B2, W.en_b2,  16, tid);
  stage(sw + O_OA_W1, W.oa_W1, 128, tid);
  stage(sw + O_OA_B1, W.oa_b1,  32, tid);
  stage(sw + O_OA_W2, W.oa_W2, 512, tid);
  stage(sw + O_OA_B2, W.oa_b2,  16, tid);
  stage(sw + O_GO_W1, W.go_W1,  64, tid);
  stage(sw + O_GO_B1, W.go_b1,  32, tid);
  stage(sw + O_GO_W2, W.go_W2, 512, tid);
  stage(sw + O_GO_B2, W.go_b2,  16, tid);
  stage(sw + O_OA_G,  W.oa_g,   16, tid);
  stage(sw + O_OA_B,  W.oa_b,   16, tid);
  stage(sw + O_GO_G,  W.go_g,   16, tid);
  stage(sw + O_GO_B,  W.go_b,   16, tid);
  stage(sw + O_A_W1,  W.a_W1, 1536, tid);
  stage(sw + O_A_B1,  W.a_b1,   32, tid);
  stage(sw + O_A_W2,  W.a_W2, 1024, tid);
  stage(sw + O_A_B2,  W.a_b2,   32, tid);
  stage(sw + O_A_W3,  W.a_W3,   64, tid);
  stage(sw + O_A_B3,  W.a_b3,    2, tid);
  __syncthreads();

  int row = blockIdx.x * 128 + pairIdx * 64 + lane;
  row = min(row, bsz - 1);
  const float* __restrict__ srow = s_input + (size_t)row * 96;

  // ---------------- self encoder: fused 4 -> 32 -> 16, relu (both roles) ----
  float self_out[16];
  {
    float2 p01 = ld2(srow + 0);
    float2 p23 = ld2(srow + 2);
#pragma unroll
    for (int d = 0; d < 16; ++d) self_out[d] = sw[O_EN_B2 + d];
#pragma unroll
    for (int j = 0; j < 32; ++j) {
      float h = sw[O_EN_B1 + j];
      h = fmaf(p01.x, sw[O_EN_W1 +  0 + j], h);
      h = fmaf(p01.y, sw[O_EN_W1 + 32 + j], h);
      h = fmaf(p23.x, sw[O_EN_W1 + 64 + j], h);
      h = fmaf(p23.y, sw[O_EN_W1 + 96 + j], h);
      h = fmaxf(h, 0.f);
#pragma unroll
      for (int d = 0; d < 16; ++d)
        self_out[d] = fmaf(h, sw[O_EN_W2 + j*16 + d], self_out[d]);
    }
#pragma unroll
    for (int d = 0; d < 16; ++d) self_out[d] = fmaxf(self_out[d], 0.f);
  }

  float other_pool[16];

  if (role == 0) {
    // ------- other agents: 15 x (4->32->16), pairs (math verbatim) -------
    float m = -3.0e38f, l = 0.f, acc[16];
#pragma unroll
    for (int d = 0; d < 16; ++d) acc[d] = 0.f;
#pragma unroll 1
    for (int kp = 0; kp < 14; kp += 2) {
      float2 a01 = ld2(srow + 4  + 2*kp);
      float2 a23 = ld2(srow + 34 + 2*kp);
      float2 b01 = ld2(srow + 4  + 2*kp + 2);
      float2 b23 = ld2(srow + 34 + 2*kp + 2);
      float enc_a[16], enc_b[16];
#pragma unroll
      for (int d = 0; d < 16; ++d) { float b2 = sw[O_OA_B2 + d]; enc_a[d] = b2; enc_b[d] = b2; }
#pragma unroll
      for (int j = 0; j < 32; ++j) {
        float w0 = sw[O_OA_W1 +  0 + j], w1 = sw[O_OA_W1 + 32 + j];
        float w2 = sw[O_OA_W1 + 64 + j], w3 = sw[O_OA_W1 + 96 + j];
        float b1 = sw[O_OA_B1 + j];
        float ha = fmaf(a01.x, w0, b1); ha = fmaf(a01.y, w1, ha);
        ha = fmaf(a23.x, w2, ha);       ha = fmaf(a23.y, w3, ha);
        ha = fmaxf(ha, 0.f);
        float hb = fmaf(b01.x, w0, b1); hb = fmaf(b01.y, w1, hb);
        hb = fmaf(b23.x, w2, hb);       hb = fmaf(b23.y, w3, hb);
        hb = fmaxf(hb, 0.f);
#pragma unroll
        for (int d = 0; d < 16; ++d) {
          float w = sw[O_OA_W2 + j*16 + d];
          enc_a[d] = fmaf(ha, w, enc_a[d]);
          enc_b[d] = fmaf(hb, w, enc_b[d]);
        }
      }
      float sa = 0.f, sb = 0.f;
#pragma unroll
      for (int d = 0; d < 16; ++d) {
        enc_a[d] = fmaxf(enc_a[d], 0.f);
        enc_b[d] = fmaxf(enc_b[d], 0.f);
        sa = fmaf(self_out[d], enc_a[d], sa);
        sb = fmaf(self_out[d], enc_b[d], sb);
      }
      sa *= 0.25f; sb *= 0.25f;
      {
        float mn = fmaxf(m, sa);
        float alpha = __expf(m - mn), w = __expf(sa - mn);
        l = fmaf(l, alpha, w);
#pragma unroll
        for (int d = 0; d < 16; ++d) acc[d] = fmaf(acc[d], alpha, w * enc_a[d]);
        m = mn;
      }
      {
        float mn = fmaxf(m, sb);
        float alpha = __expf(m - mn), w = __expf(sb - mn);
        l = fmaf(l, alpha, w);
#pragma unroll
        for (int d = 0; d < 16; ++d) acc[d] = fmaf(acc[d], alpha, w * enc_b[d]);
        m = mn;
      }
    }
    { // last entity k = 14
      float2 a01 = ld2(srow + 4  + 2*14);
      float2 a23 = ld2(srow + 34 + 2*14);
      float enc[16];
#pragma unroll
      for (int d = 0; d < 16; ++d) enc[d] = sw[O_OA_B2 + d];
#pragma unroll
      for (int j = 0; j < 32; ++j) {
        float h = sw[O_OA_B1 + j];
        h = fmaf(a01.x, sw[O_OA_W1 +  0 + j], h);
        h = fmaf(a01.y, sw[O_OA_W1 + 32 + j], h);
        h = fmaf(a23.x, sw[O_OA_W1 + 64 + j], h);
        h = fmaf(a23.y, sw[O_OA_W1 + 96 + j], h);
        h = fmaxf(h, 0.f);
#pragma unroll
        for (int d = 0; d < 16; ++d)
          enc[d] = fmaf(h, sw[O_OA_W2 + j*16 + d], enc[d]);
      }
      float s = 0.f;
#pragma unroll
      for (int d = 0; d < 16; ++d) {
        enc[d] = fmaxf(enc[d], 0.f);
        s = fmaf(self_out[d], enc[d], s);
      }
      s *= 0.25f;
      float mn = fmaxf(m, s);
      float alpha = __expf(m - mn), w = __expf(s - mn);
      l = fmaf(l, alpha, w);
#pragma unroll
      for (int d = 0; d < 16; ++d) acc[d] = fmaf(acc[d], alpha, w * enc[d]);
      m = mn;
    }
    float inv = 1.f / l;
    float mu = 0.f;
#pragma unroll
    for (int d = 0; d < 16; ++d) { acc[d] *= inv; mu += acc[d]; }
    mu *= (1.f / 16.f);
    float var = 0.f;
#pragma unroll
    for (int d = 0; d < 16; ++d) { float x = acc[d] - mu; var = fmaf(x, x, var); }
    var *= (1.f / 16.f);
    float rstd = rsqrtf(var + LN_EPS);
#pragma unroll
    for (int d = 0; d < 16; ++d)
      other_pool[d] = fmaxf(fmaf((acc[d] - mu) * rstd, sw[O_OA_G + d], sw[O_OA_B + d]), 0.f);
  } else {
    // ------- food: 16 x (2->32->16), pairs (math verbatim) -> LDS -------
    float m = -3.0e38f, l = 0.f, acc[16];
#pragma unroll
    for (int d = 0; d < 16; ++d) acc[d] = 0.f;
#pragma unroll 1
    for (int kp = 0; kp < 16; kp += 2) {
      float2 fa = ld2(srow + 64 + 2*kp);
      float2 fb = ld2(srow + 64 + 2*kp + 2);
      float enc_a[16], enc_b[16];
#pragma unroll
      for (int d = 0; d < 16; ++d) { float b2 = sw[O_GO_B2 + d]; enc_a[d] = b2; enc_b[d] = b2; }
#pragma unroll
      for (int j = 0; j < 32; ++j) {
        float w0 = sw[O_GO_W1 + 0 + j], w1 = sw[O_GO_W1 + 32 + j];
        float b1 = sw[O_GO_B1 + j];
        float ha = fmaf(fa.x, w0, b1); ha = fmaf(fa.y, w1, ha); ha = fmaxf(ha, 0.f);
        float hb = fmaf(fb.x, w0, b1); hb = fmaf(fb.y, w1, hb); hb = fmaxf(hb, 0.f);
#pragma unroll
        for (int d = 0; d < 16; ++d) {
          float w = sw[O_GO_W2 + j*16 + d];
          enc_a[d] = fmaf(ha, w, enc_a[d]);
          enc_b[d] = fmaf(hb, w, enc_b[d]);
        }
      }
      float sa = 0.f, sb = 0.f;
#pragma unroll
      for (int d = 0; d < 16; ++d) {
        enc_a[d] = fmaxf(enc_a[d], 0.f);
        enc_b[d] = fmaxf(enc_b[d], 0.f);
        sa = fmaf(self_out[d], enc_a[d], sa);
        sb = fmaf(self_out[d], enc_b[d], sb);
      }
      sa *= 0.25f; sb *= 0.25f;
      {
        float mn = fmaxf(m, sa);
        float alpha = __expf(m - mn), w = __expf(sa - mn);
        l = fmaf(l, alpha, w);
#pragma unroll
        for (int d = 0; d < 16; ++d) acc[d] = fmaf(acc[d], alpha, w * enc_a[d]);
        m = mn;
      }
      {
        float mn = fmaxf(m, sb);
        float alpha = __expf(m - mn), w = __expf(sb - mn);
        l = fmaf(l, alpha, w);
#pragma unroll
        for (int d = 0; d < 16; ++d) acc[d] = fmaf(acc[d], alpha, w * enc_b[d]);
        m = mn;
      }
    }
    float inv = 1.f / l;
    float mu = 0.f;
#pragma unroll
    for (int d = 0; d < 16; ++d) { acc[d] *= inv; mu += acc[d]; }
    mu *= (1.f / 16.f);
    float var = 0.f;
#pragma unroll
    for (int d = 0; d < 16; ++d) { float x = acc[d] - mu; var = fmaf(x, x, var); }
    var *= (1.f / 16.f);
    float rstd = rsqrtf(var + LN_EPS);
#pragma unroll
    for (int d = 0; d < 16; ++d) {
      float fp = fmaxf(fmaf((acc[d] - mu) * rstd, sw[O_GO_G + d], sw[O_GO_B + d]), 0.f);
      fpool[pairIdx][lane][d] = fp;
    }
  }

  __syncthreads();
  if (role != 0) return;

  // ------- action head (role 0): 48 -> 32 -> 32 -> 2 -------
  float food_pool[16];
#pragma unroll
  for (int d = 0; d < 16; ++d) food_pool[d] = fpool[pairIdx][lane][d];

  float h1[32];
#pragma unroll
  for (int j = 0; j < 32; ++j) h1[j] = sw[O_A_B1 + j];
#pragma unroll
  for (int c = 0; c < 16; ++c) {
    float v = self_out[c];
#pragma unroll
    for (int j = 0; j < 32; ++j) h1[j] = fmaf(v, sw[O_A_W1 + c*32 + j], h1[j]);
  }
#pragma unroll
  for (int c = 0; c < 16; ++c) {
    float v = food_pool[c];
#pragma unroll
    for (int j = 0; j < 32; ++j) h1[j] = fmaf(v, sw[O_A_W1 + (16 + c)*32 + j], h1[j]);
  }
#pragma unroll
  for (int c = 0; c < 16; ++c) {
    float v = other_pool[c];
#pragma unroll
    for (int j = 0; j < 32; ++j) h1[j] = fmaf(v, sw[O_A_W1 + (32 + c)*32 + j], h1[j]);
  }
#pragma unroll
  for (int j = 0; j < 32; ++j) h1[j] = fmaxf(h1[j], 0.01f * h1[j]);   // leaky

  float h2[32];
#pragma unroll
  for (int j = 0; j < 32; ++j) h2[j] = sw[O_A_B2 + j];
#pragma unroll
  for (int c = 0; c < 32; ++c) {
    float v = h1[c];
#pragma unroll
    for (int j = 0; j < 32; ++j) h2[j] = fmaf(v, sw[O_A_W2 + c*32 + j], h2[j]);
  }
#pragma unroll
  for (int j = 0; j < 32; ++j) h2[j] = fmaxf(h2[j], 0.01f * h2[j]);

  float o0 = sw[O_A_B3 + 0], o1 = sw[O_A_B3 + 1];
#pragma unroll
  for (int c = 0; c < 32; ++c) {
    o0 = fmaf(h2[c], sw[O_A_W3 + c*2 + 0], o0);
    o1 = fmaf(h2[c], sw[O_A_W3 + c*2 + 1], o1);
  }
  o0 = tanhf(o0);
  o1 = tanhf(o1);

  reinterpret_cast<float2*>(out)[row] = make_float2(o0, o1);
}

extern "C" void kernel_launch(void* const* d_in, const int* in_sizes, int n_in,
                              void* d_out, int out_size, void* d_ws, size_t ws_size,
                              hipStream_t stream) {
  const float* s_input = (const float*)d_in[0];
  Weights W;
  W.en_W1 = (const float*)d_in[1];  W.en_b1 = (const float*)d_in[2];
  W.en_W2 = (const float*)d_in[3];  W.en_b2 = (const float*)d_in[4];
  W.oa_W1 = (const float*)d_in[5];  W.oa_b1 = (const float*)d_in[6];
  W.oa_W2 = (const float*)d_in[7];  W.oa_b2 = (const float*)d_in[8];
  W.go_W1 = (const float*)d_in[9];  W.go_b1 = (const float*)d_in[10];
  W.go_W2 = (const float*)d_in[11]; W.go_b2 = (const float*)d_in[12];
  W.oa_g  = (const float*)d_in[13]; W.oa_b  = (const float*)d_in[14];
  W.go_g  = (const float*)d_in[15]; W.go_b  = (const float*)d_in[16];
  W.a_W1  = (const float*)d_in[17]; W.a_b1  = (const float*)d_in[18];
  W.a_W2  = (const float*)d_in[19]; W.a_b2  = (const float*)d_in[20];
  W.a_W3  = (const float*)d_in[21]; W.a_b3  = (const float*)d_in[22];

  const int bsz = in_sizes[0] / 96;          // 262144
  const int blocks = (bsz + 127) / 128;      // 128 rows per block (2 groups x 2 waves)
  actor_fwd<<<blocks, 256, 0, stream>>>(s_input, W, (float*)d_out, bsz);
}

// Round 2
// 423.731 us; speedup vs baseline: 3.5241x; 3.5241x over previous
//
#include <hip/hip_runtime.h>

// Actor_attf_single — MI355X (gfx950)
// R11: revert to R8 single-wave structure (best known: 329us; R9 role-split
// was 352, R10 LDS-weights was 1445 via VGPR-256 + scratch spills).
// Ledger lessons:
//   - weights MUST stay on the s_load/SGPR path (zero VGPR cost); LDS
//     weights -> ds_read -> VGPR explosion -> spills (R10: WRITE 540MB).
//   - TLP is capped at 4 waves/SIMD (4096 row-waves / 1024 SIMDs); more
//     waves via role-split did NOT help (R9 > R8).
// R11 lever: ENTITY BATCHING. R8 processed 2 entities per weight pass;
// each pass re-streams 672 weight dwords through SGPRs (~10 lgkmcnt drain
// points) and exposes input-load latency at each pass top. Batch 3 ("other",
// 5 passes for 15 entities) / 4 ("food", 4 passes for 16) amortizes the
// weight re-stream 1.6-2x with identical per-entity math:
//   - per-entity FMA order verbatim R8 => bitwise-identical, absmax must
//     stay 0.00390625
//   - softmax updates strictly in entity order (0..14 / 0..15)
//   - live set ~110 VGPR; __launch_bounds__(256,4) caps at 128 so the R10
//     spill mode cannot recur. No LDS at all.

#define LN_EPS 1e-5f

struct Weights {
  const float* __restrict__ en_W1; const float* __restrict__ en_b1;
  const float* __restrict__ en_W2; const float* __restrict__ en_b2;
  const float* __restrict__ oa_W1; const float* __restrict__ oa_b1;
  const float* __restrict__ oa_W2; const float* __restrict__ oa_b2;
  const float* __restrict__ go_W1; const float* __restrict__ go_b1;
  const float* __restrict__ go_W2; const float* __restrict__ go_b2;
  const float* __restrict__ oa_g;  const float* __restrict__ oa_b;
  const float* __restrict__ go_g;  const float* __restrict__ go_b;
  const float* __restrict__ a_W1;  const float* __restrict__ a_b1;
  const float* __restrict__ a_W2;  const float* __restrict__ a_b2;
  const float* __restrict__ a_W3;  const float* __restrict__ a_b3;
};

__device__ __forceinline__ float2 ld2(const float* __restrict__ p) {
  return *reinterpret_cast<const float2*>(p);
}

__global__ __launch_bounds__(256, 4)
void actor_fwd(const float* __restrict__ s_input, Weights W,
               float* __restrict__ out, int bsz) {
  const int lane = threadIdx.x & 63;
  const int wv   = threadIdx.x >> 6;        // 0..3, independent waves
  int row = blockIdx.x * 256 + wv * 64 + lane;
  row = min(row, bsz - 1);
  const float* __restrict__ srow = s_input + (size_t)row * 96;

  // ---------------- self encoder: fused 4 -> 32 -> 16, relu ----------------
  float self_out[16];
  {
    float2 p01 = ld2(srow + 0);
    float2 p23 = ld2(srow + 2);
#pragma unroll
    for (int d = 0; d < 16; ++d) self_out[d] = W.en_b2[d];
#pragma unroll
    for (int j = 0; j < 32; ++j) {
      float h = W.en_b1[j];
      h = fmaf(p01.x, W.en_W1[ 0 + j], h);
      h = fmaf(p01.y, W.en_W1[32 + j], h);
      h = fmaf(p23.x, W.en_W1[64 + j], h);
      h = fmaf(p23.y, W.en_W1[96 + j], h);
      h = fmaxf(h, 0.f);
#pragma unroll
      for (int d = 0; d < 16; ++d)
        self_out[d] = fmaf(h, W.en_W2[j*16 + d], self_out[d]);
    }
#pragma unroll
    for (int d = 0; d < 16; ++d) self_out[d] = fmaxf(self_out[d], 0.f);
  }

  // ------- other agents: 15 x (4->32->16), batches of 3 ------------------
  float other_pool[16];
  {
    float m = -3.0e38f, l = 0.f, acc[16];
#pragma unroll
    for (int d = 0; d < 16; ++d) acc[d] = 0.f;

#pragma unroll 1
    for (int k0 = 0; k0 < 15; k0 += 3) {
      float2 i01[3], i23[3];
#pragma unroll
      for (int e = 0; e < 3; ++e) {
        i01[e] = ld2(srow + 4  + 2*(k0 + e));
        i23[e] = ld2(srow + 34 + 2*(k0 + e));
      }
      float enc[3][16];
#pragma unroll
      for (int d = 0; d < 16; ++d) {
        float b2 = W.oa_b2[d];
#pragma unroll
        for (int e = 0; e < 3; ++e) enc[e][d] = b2;
      }
#pragma unroll
      for (int j = 0; j < 32; ++j) {
        float w0 = W.oa_W1[ 0 + j], w1 = W.oa_W1[32 + j];
        float w2 = W.oa_W1[64 + j], w3 = W.oa_W1[96 + j];
        float b1 = W.oa_b1[j];
        float h[3];
#pragma unroll
        for (int e = 0; e < 3; ++e) {
          float t = fmaf(i01[e].x, w0, b1);
          t = fmaf(i01[e].y, w1, t);
          t = fmaf(i23[e].x, w2, t);
          t = fmaf(i23[e].y, w3, t);
          h[e] = fmaxf(t, 0.f);
        }
#pragma unroll
        for (int d = 0; d < 16; ++d) {
          float w = W.oa_W2[j*16 + d];
#pragma unroll
          for (int e = 0; e < 3; ++e) enc[e][d] = fmaf(h[e], w, enc[e][d]);
        }
      }
      // per-entity epilogue, strictly in entity order (bitwise == R8)
#pragma unroll
      for (int e = 0; e < 3; ++e) {
        float s = 0.f;
#pragma unroll
        for (int d = 0; d < 16; ++d) {
          enc[e][d] = fmaxf(enc[e][d], 0.f);
          s = fmaf(self_out[d], enc[e][d], s);
        }
        s *= 0.25f;
        float mn = fmaxf(m, s);
        float alpha = __expf(m - mn), w = __expf(s - mn);
        l = fmaf(l, alpha, w);
#pragma unroll
        for (int d = 0; d < 16; ++d) acc[d] = fmaf(acc[d], alpha, w * enc[e][d]);
        m = mn;
      }
    }

    float inv = 1.f / l;
    float mu = 0.f;
#pragma unroll
    for (int d = 0; d < 16; ++d) { acc[d] *= inv; mu += acc[d]; }
    mu *= (1.f / 16.f);
    float var = 0.f;
#pragma unroll
    for (int d = 0; d < 16; ++d) { float x = acc[d] - mu; var = fmaf(x, x, var); }
    var *= (1.f / 16.f);
    float rstd = rsqrtf(var + LN_EPS);
#pragma unroll
    for (int d = 0; d < 16; ++d)
      other_pool[d] = fmaxf(fmaf((acc[d] - mu) * rstd, W.oa_g[d], W.oa_b[d]), 0.f);
  }

  // ------- food: 16 x (2->32->16), batches of 4 --------------------------
  float food_pool[16];
  {
    float m = -3.0e38f, l = 0.f, acc[16];
#pragma unroll
    for (int d = 0; d < 16; ++d) acc[d] = 0.f;

#pragma unroll 1
    for (int k0 = 0; k0 < 16; k0 += 4) {
      float2 fi[4];
#pragma unroll
      for (int e = 0; e < 4; ++e) fi[e] = ld2(srow + 64 + 2*(k0 + e));
      float enc[4][16];
#pragma unroll
      for (int d = 0; d < 16; ++d) {
        float b2 = W.go_b2[d];
#pragma unroll
        for (int e = 0; e < 4; ++e) enc[e][d] = b2;
      }
#pragma unroll
      for (int j = 0; j < 32; ++j) {
        float w0 = W.go_W1[0 + j], w1 = W.go_W1[32 + j];
        float b1 = W.go_b1[j];
        float h[4];
#pragma unroll
        for (int e = 0; e < 4; ++e) {
          float t = fmaf(fi[e].x, w0, b1);
          t = fmaf(fi[e].y, w1, t);
          h[e] = fmaxf(t, 0.f);
        }
#pragma unroll
        for (int d = 0; d < 16; ++d) {
          float w = W.go_W2[j*16 + d];
#pragma unroll
          for (int e = 0; e < 4; ++e) enc[e][d] = fmaf(h[e], w, enc[e][d]);
        }
      }
      // per-entity epilogue, strictly in entity order (bitwise == R8)
#pragma unroll
      for (int e = 0; e < 4; ++e) {
        float s = 0.f;
#pragma unroll
        for (int d = 0; d < 16; ++d) {
          enc[e][d] = fmaxf(enc[e][d], 0.f);
          s = fmaf(self_out[d], enc[e][d], s);
        }
        s *= 0.25f;
        float mn = fmaxf(m, s);
        float alpha = __expf(m - mn), w = __expf(s - mn);
        l = fmaf(l, alpha, w);
#pragma unroll
        for (int d = 0; d < 16; ++d) acc[d] = fmaf(acc[d], alpha, w * enc[e][d]);
        m = mn;
      }
    }

    float inv = 1.f / l;
    float mu = 0.f;
#pragma unroll
    for (int d = 0; d < 16; ++d) { acc[d] *= inv; mu += acc[d]; }
    mu *= (1.f / 16.f);
    float var = 0.f;
#pragma unroll
    for (int d = 0; d < 16; ++d) { float x = acc[d] - mu; var = fmaf(x, x, var); }
    var *= (1.f / 16.f);
    float rstd = rsqrtf(var + LN_EPS);
#pragma unroll
    for (int d = 0; d < 16; ++d)
      food_pool[d] = fmaxf(fmaf((acc[d] - mu) * rstd, W.go_g[d], W.go_b[d]), 0.f);
  }

  // ------- action head: 48 -> 32 -> 32 -> 2 ------------------------------
  float h1[32];
#pragma unroll
  for (int j = 0; j < 32; ++j) h1[j] = W.a_b1[j];
#pragma unroll
  for (int c = 0; c < 16; ++c) {
    float v = self_out[c];
#pragma unroll
    for (int j = 0; j < 32; ++j) h1[j] = fmaf(v, W.a_W1[c*32 + j], h1[j]);
  }
#pragma unroll
  for (int c = 0; c < 16; ++c) {
    float v = food_pool[c];
#pragma unroll
    for (int j = 0; j < 32; ++j) h1[j] = fmaf(v, W.a_W1[(16 + c)*32 + j], h1[j]);
  }
#pragma unroll
  for (int c = 0; c < 16; ++c) {
    float v = other_pool[c];
#pragma unroll
    for (int j = 0; j < 32; ++j) h1[j] = fmaf(v, W.a_W1[(32 + c)*32 + j], h1[j]);
  }
#pragma unroll
  for (int j = 0; j < 32; ++j) h1[j] = fmaxf(h1[j], 0.01f * h1[j]);   // leaky

  float h2[32];
#pragma unroll
  for (int j = 0; j < 32; ++j) h2[j] = W.a_b2[j];
#pragma unroll
  for (int c = 0; c < 32; ++c) {
    float v = h1[c];
#pragma unroll
    for (int j = 0; j < 32; ++j) h2[j] = fmaf(v, W.a_W2[c*32 + j], h2[j]);
  }
#pragma unroll
  for (int j = 0; j < 32; ++j) h2[j] = fmaxf(h2[j], 0.01f * h2[j]);

  float o0 = W.a_b3[0], o1 = W.a_b3[1];
#pragma unroll
  for (int c = 0; c < 32; ++c) {
    o0 = fmaf(h2[c], W.a_W3[c*2 + 0], o0);
    o1 = fmaf(h2[c], W.a_W3[c*2 + 1], o1);
  }
  o0 = tanhf(o0);
  o1 = tanhf(o1);

  reinterpret_cast<float2*>(out)[row] = make_float2(o0, o1);
}

extern "C" void kernel_launch(void* const* d_in, const int* in_sizes, int n_in,
                              void* d_out, int out_size, void* d_ws, size_t ws_size,
                              hipStream_t stream) {
  const float* s_input = (const float*)d_in[0];
  Weights W;
  W.en_W1 = (const float*)d_in[1];  W.en_b1 = (const float*)d_in[2];
  W.en_W2 = (const float*)d_in[3];  W.en_b2 = (const float*)d_in[4];
  W.oa_W1 = (const float*)d_in[5];  W.oa_b1 = (const float*)d_in[6];
  W.oa_W2 = (const float*)d_in[7];  W.oa_b2 = (const float*)d_in[8];
  W.go_W1 = (const float*)d_in[9];  W.go_b1 = (const float*)d_in[10];
  W.go_W2 = (const float*)d_in[11]; W.go_b2 = (const float*)d_in[12];
  W.oa_g  = (const float*)d_in[13]; W.oa_b  = (const float*)d_in[14];
  W.go_g  = (const float*)d_in[15]; W.go_b  = (const float*)d_in[16];
  W.a_W1  = (const float*)d_in[17]; W.a_b1  = (const float*)d_in[18];
  W.a_W2  = (const float*)d_in[19]; W.a_b2  = (const float*)d_in[20];
  W.a_W3  = (const float*)d_in[21]; W.a_b3  = (const float*)d_in[22];

  const int bsz = in_sizes[0] / 96;          // 262144
  const int blocks = (bsz + 255) / 256;      // 256 rows per block, 4 waves
  actor_fwd<<<blocks, 256, 0, stream>>>(s_input, W, (float*)d_out, bsz);
}